// Round 16
// baseline (282.380 us; speedup 1.0000x reference)
//
#include <hip/hip_runtime.h>

typedef short bf16x8 __attribute__((ext_vector_type(8)));
typedef float f32x4 __attribute__((ext_vector_type(4)));
typedef unsigned short u16x2 __attribute__((ext_vector_type(2)));
typedef unsigned short u16x4 __attribute__((ext_vector_type(4)));
typedef unsigned short u16x8 __attribute__((ext_vector_type(8)));

static constexpr int N_NODES = 50000;
static constexpr int N_EDGES = 800000;
static constexpr int D_NODE = 128;
static constexpr int D_EDGE = 64;

// workspace layout (bytes)
static constexpr size_t START_OFF = 0;                       // (N_NODES+1) ints
static constexpr size_t FILL_OFF  = 262144;                  // N_NODES ints
static constexpr size_t META_OFF  = 524288;                  // N_EDGES int4 (also bsum scratch)
static constexpr size_t NF16_OFF  = META_OFF + (size_t)N_EDGES * 16;
static constexpr size_t W0F_OFF   = NF16_OFF + (size_t)N_NODES * D_NODE * 2;
static constexpr size_t W1F_OFF   = W0F_OFF + 4096 * 2;
static constexpr size_t WS_NEED   = W1F_OFF + 8192 * 2;

__device__ __forceinline__ unsigned short f2bf(float f) {
    union { float f; unsigned u; } v; v.f = f;
    return (unsigned short)((v.u + 0x7fffu + ((v.u >> 16) & 1u)) >> 16);
}
__device__ __forceinline__ float bf2f(unsigned short h) {
    union { unsigned u; float f; } v; v.u = ((unsigned)h) << 16;
    return v.f;
}

// =============== preprocessing: CSR permutation of edges by dst ==============
__global__ void kh(const int* __restrict__ dst, int* __restrict__ start) {
    int e = blockIdx.x * blockDim.x + threadIdx.x;
    if (e < N_EDGES) atomicAdd(&start[dst[e] + 1], 1);
}

__global__ __launch_bounds__(256) void ks1(const int* __restrict__ a, int* __restrict__ bsum, int n) {
    __shared__ int sd[256];
    const int t = threadIdx.x;
    int i = blockIdx.x * 256 + t;
    sd[t] = (i < n) ? a[i] : 0;
    __syncthreads();
    for (int off = 128; off > 0; off >>= 1) {
        if (t < off) sd[t] += sd[t + off];
        __syncthreads();
    }
    if (t == 0) bsum[blockIdx.x] = sd[0];
}

__global__ __launch_bounds__(256) void ks2(int* __restrict__ bsum, int nb) {
    __shared__ int sd[256];
    const int t = threadIdx.x;
    sd[t] = (t < nb) ? bsum[t] : 0;
    __syncthreads();
    for (int off = 1; off < 256; off <<= 1) {
        int v = (t >= off) ? sd[t - off] : 0;
        __syncthreads();
        sd[t] += v;
        __syncthreads();
    }
    if (t < nb) bsum[t] = sd[t];
}

__global__ __launch_bounds__(256) void ks3(const int* __restrict__ bsum,
                                           int* __restrict__ start, int* __restrict__ fill, int n) {
    __shared__ int sd[256];
    const int t = threadIdx.x;
    const int i = blockIdx.x * 256 + t;
    sd[t] = (i < n) ? start[i] : 0;
    __syncthreads();
    for (int off = 1; off < 256; off <<= 1) {
        int v = (t >= off) ? sd[t - off] : 0;
        __syncthreads();
        sd[t] += v;
        __syncthreads();
    }
    const int off0 = (blockIdx.x > 0) ? bsum[blockIdx.x - 1] : 0;
    const int val = sd[t] + off0;
    if (i < n) start[i] = val;
    if (i < N_NODES) fill[i] = val;
}

// build CSR order: meta[p] = (edge, src, dst, 0) — one 16B scatter per edge
__global__ void kpos(const int* __restrict__ dst, const int* __restrict__ src,
                     int* __restrict__ fill, int4* __restrict__ meta) {
    int e = blockIdx.x * blockDim.x + threadIdx.x;
    if (e < N_EDGES) {
        int d = dst[e];
        int p = atomicAdd(&fill[d], 1);
        meta[p] = int4{e, src[e], d, 0};
    }
}

// =============== prep (merged): acc init + nf16t transpose + weight frags ====
__global__ __launch_bounds__(256) void k_prep(const float* __restrict__ nf,
                                              float* __restrict__ out,
                                              unsigned short* __restrict__ nf16t,
                                              const float* __restrict__ W0,
                                              const float* __restrict__ W1,
                                              unsigned short* __restrict__ w0frag,
                                              unsigned short* __restrict__ w1frag,
                                              int nprep) {
    if ((int)blockIdx.x >= nprep) {
        const int f = ((int)blockIdx.x - nprep) * 256 + threadIdx.x;   // 0..8191
        if (f < 4096) {
            int j = f & 7, lane = (f >> 3) & 63, nt = (f >> 9) & 3, ks = (f >> 11) & 1;
            int k = ks * 32 + ((lane >> 4) << 2) + (j & 3) + ((j & 4) << 2);
            int n = nt * 16 + (lane & 15);
            w0frag[f] = f2bf(W0[k * 64 + n]);
        }
        if (f < 8192) {
            int j = f & 7, lane = (f >> 3) & 63, nt = (f >> 9) & 7, ks = (f >> 12) & 1;
            int k = ks * 32 + ((lane >> 4) << 2) + (j & 3) + ((j & 4) << 2);
            int n = nt * 16 + (lane & 15);
            w1frag[f] = f2bf(W1[k * 128 + n]);
        }
        return;
    }
    const int tid = threadIdx.x;
    const int lm = tid & 15;
    const int node = blockIdx.x * 16 + (tid >> 4);
    if (node >= N_NODES) return;
    const float* nrow = nf + (size_t)node * D_NODE;
    float* orow = out + (size_t)node * D_NODE;
    f32x4 y0 = *(const f32x4*)(nrow + lm * 8);
    f32x4 y1 = *(const f32x4*)(nrow + lm * 8 + 4);
    *(f32x4*)(orow + lm * 8) = y0;
    *(f32x4*)(orow + lm * 8 + 4) = y1;
    u16x8 tv;
#pragma unroll
    for (int nt = 0; nt < 8; ++nt) tv[nt] = f2bf(nrow[nt * 16 + lm]);
    *(u16x8*)(nf16t + (size_t)node * D_NODE + lm * 8) = tv;
}

// =============== fused: edge MLP (CSR order) + mT segment reduce, PIPELINED ==
// 256 threads, 4 waves, 4 tiles/wave, fully unrolled with cur/next rotation:
// tile t+1's meta/ef/gather loads are issued before tile t's combine+reduce,
// so their latency drains under the reduce phase (vmcnt is in-order).
// Reduce is the r14 mT form (lane-parallel over columns — r15 showed the
// register form is slower). Weights from GLOBAL (L1-resident, 24KB).
__global__ __launch_bounds__(256) void k_fused(
    const float* __restrict__ ef, const unsigned short* __restrict__ nf16t,
    const unsigned short* __restrict__ w0frag, const unsigned short* __restrict__ w1frag,
    const float* __restrict__ b0, const float* __restrict__ b1,
    const int4* __restrict__ meta, float* __restrict__ out)
{
    __shared__ __align__(16) unsigned short hT[4][16][72];    // 9 KB
    __shared__ __align__(16) unsigned short mT[4][16][136];   // 17 KB

    const int tid = threadIdx.x;

    // bijective XCD swizzle (m204): contiguous CSR ranges stay on one XCD
    int bid = blockIdx.x;
    {
        const int nwg = gridDim.x;            // 3125
        const int q = nwg >> 3, rr = nwg & 7; // q=390, rr=5
        const int xcd = bid & 7, j = bid >> 3;
        bid = (xcd < rr ? xcd * (q + 1) : rr * (q + 1) + (xcd - rr) * q) + j;
    }

    const int wv = tid >> 6;
    const int lane = tid & 63;
    const int lm = lane & 15;
    const int lq = lane >> 4;

    float b0r[4], b1r[8];
#pragma unroll
    for (int nt = 0; nt < 4; ++nt) b0r[nt] = b0[nt * 16 + lm];
#pragma unroll
    for (int nt = 0; nt < 8; ++nt) b1r[nt] = b1[nt * 16 + lm];

    const bf16x8* w0v = (const bf16x8*)w0frag;   // global, L1-hit after 1st touch
    const bf16x8* w1v = (const bf16x8*)w1frag;

    const int wtile0 = (bid * 4 + wv) * 4;

    // ---- prologue: tile 0 meta + ef + gather ----
    int4 mcur = meta[(size_t)(wtile0 + 0) * 16 + lm];
    f32x4 a0, a1, a2, a3;
    {
        const f32x4* er = (const f32x4*)(ef + (size_t)mcur.x * D_EDGE);
        a0 = er[lq]; a1 = er[4 + lq]; a2 = er[8 + lq]; a3 = er[12 + lq];
    }
    u16x8 ngb[4];
#pragma unroll
    for (int r = 0; r < 4; ++r) {
        const int s_row = __shfl(mcur.y, lq * 4 + r);
        ngb[r] = *(const u16x8*)(nf16t + (size_t)s_row * D_NODE + lm * 8);
    }

#pragma unroll
    for (int t = 0; t < 4; ++t) {
        // ---- prefetch next tile's meta (independent; long lead time) ----
        int4 mnext;
        if (t < 3) mnext = meta[(size_t)(wtile0 + t + 1) * 16 + lm];

        // ---- pack A fragments from current ef ----
        bf16x8 af0, af1;
#pragma unroll
        for (int j = 0; j < 4; ++j) {
            af0[j] = (short)f2bf(a0[j]); af0[j + 4] = (short)f2bf(a1[j]);
            af1[j] = (short)f2bf(a2[j]); af1[j + 4] = (short)f2bf(a3[j]);
        }

        // ---- layer 1 ----
        f32x4 h[4];
#pragma unroll
        for (int nt = 0; nt < 4; ++nt) h[nt] = f32x4{0.f, 0.f, 0.f, 0.f};
#pragma unroll
        for (int nt = 0; nt < 4; ++nt) {
            h[nt] = __builtin_amdgcn_mfma_f32_16x16x32_bf16(af0, w0v[(0 * 4 + nt) * 64 + lane], h[nt], 0, 0, 0);
            h[nt] = __builtin_amdgcn_mfma_f32_16x16x32_bf16(af1, w0v[(1 * 4 + nt) * 64 + lane], h[nt], 0, 0, 0);
        }
#pragma unroll
        for (int nt = 0; nt < 4; ++nt)
#pragma unroll
            for (int r = 0; r < 4; ++r) {
                float x = h[nt][r] + b0r[nt];
                hT[wv][lq * 4 + r][nt * 16 + lm] = f2bf(fmaxf(x, 0.f));
            }

        const unsigned short* hrow = &hT[wv][lm][0];
        u16x4 p0 = *(const u16x4*)(hrow + lq * 4);
        u16x4 p1 = *(const u16x4*)(hrow + 16 + lq * 4);
        u16x4 p2 = *(const u16x4*)(hrow + 32 + lq * 4);
        u16x4 p3 = *(const u16x4*)(hrow + 48 + lq * 4);
        bf16x8 g0, g1;
#pragma unroll
        for (int j = 0; j < 4; ++j) {
            g0[j] = (short)p0[j]; g0[j + 4] = (short)p1[j];
            g1[j] = (short)p2[j]; g1[j + 4] = (short)p3[j];
        }

        // ---- layer 2 ----
        f32x4 o[8];
#pragma unroll
        for (int nt = 0; nt < 8; ++nt) o[nt] = f32x4{0.f, 0.f, 0.f, 0.f};
#pragma unroll
        for (int nt = 0; nt < 8; ++nt) {
            o[nt] = __builtin_amdgcn_mfma_f32_16x16x32_bf16(g0, w1v[(0 * 8 + nt) * 64 + lane], o[nt], 0, 0, 0);
            o[nt] = __builtin_amdgcn_mfma_f32_16x16x32_bf16(g1, w1v[(1 * 8 + nt) * 64 + lane], o[nt], 0, 0, 0);
        }

        // ---- prefetch next tile's ef + gather (drains under combine+reduce) --
        f32x4 na0, na1, na2, na3;
        u16x8 nngb[4];
        if (t < 3) {
            const f32x4* ern = (const f32x4*)(ef + (size_t)mnext.x * D_EDGE);
            na0 = ern[lq]; na1 = ern[4 + lq]; na2 = ern[8 + lq]; na3 = ern[12 + lq];
#pragma unroll
            for (int r = 0; r < 4; ++r) {
                const int s_row = __shfl(mnext.y, lq * 4 + r);
                nngb[r] = *(const u16x8*)(nf16t + (size_t)s_row * D_NODE + lm * 8);
            }
        }

        // ---- combine: e = relu(o+b1); m = relu(x_src + e) -> mT (per-wave) --
#pragma unroll
        for (int nt = 0; nt < 8; ++nt)
#pragma unroll
            for (int r = 0; r < 4; ++r) {
                float e2 = fmaxf(o[nt][r] + b1r[nt], 0.f);
                float x = e2 + bf2f(ngb[r][nt]);
                mT[wv][lq * 4 + r][nt * 16 + lm] = f2bf(fmaxf(x, 0.f));
            }

        // wave-local LDS RAW: drain LDS writes, pin ordering (no block barrier)
        asm volatile("s_waitcnt lgkmcnt(0)" ::: "memory");
        __builtin_amdgcn_sched_barrier(0);

        // ---- inline segment-sum: lane owns cols {lane*2, lane*2+1} ----
        const int d_m = mcur.z;
        float acc0 = 0.f, acc1 = 0.f;
        int dprev = __shfl(d_m, 0);
#pragma unroll
        for (int r = 0; r < 16; ++r) {
            const int dr = __shfl(d_m, r);
            if (dr != dprev) {                    // wave-uniform condition
                float* orow = out + (size_t)dprev * D_NODE + lane * 2;
                unsafeAtomicAdd(orow, acc0);
                unsafeAtomicAdd(orow + 1, acc1);
                acc0 = 0.f; acc1 = 0.f; dprev = dr;
            }
            const u16x2 v = *(const u16x2*)&mT[wv][r][lane * 2];   // typed load
            acc0 += bf2f(v[0]);
            acc1 += bf2f(v[1]);
        }
        float* orow = out + (size_t)dprev * D_NODE + lane * 2;
        unsafeAtomicAdd(orow, acc0);
        unsafeAtomicAdd(orow + 1, acc1);

        asm volatile("" ::: "memory");   // keep next tile's mT writes below these reads

        // ---- rotate cur <- next (pure renaming under full unroll) ----
        if (t < 3) {
            mcur = mnext;
            a0 = na0; a1 = na1; a2 = na2; a3 = na3;
#pragma unroll
            for (int r = 0; r < 4; ++r) ngb[r] = nngb[r];
        }
    }
}

// =============== fallback path (atomic scatter), known-good ==================
__global__ void k_copy(const f32x4* __restrict__ s, f32x4* __restrict__ d, int n4) {
    int stride = gridDim.x * blockDim.x;
    for (int i = blockIdx.x * blockDim.x + threadIdx.x; i < n4; i += stride)
        d[i] = s[i];
}

__global__ __launch_bounds__(256) void k_edge(
    const float* __restrict__ ef, const float* __restrict__ nf,
    const float* __restrict__ W0, const float* __restrict__ b0,
    const float* __restrict__ W1, const float* __restrict__ b1,
    const int* __restrict__ src, const int* __restrict__ dst,
    float* __restrict__ acc)
{
    __shared__ unsigned short w0f[2 * 4 * 64 * 8];
    __shared__ unsigned short w1f[2 * 8 * 64 * 8];
    __shared__ unsigned short hT[4][16][72];

    const int tid = threadIdx.x;
    for (int f = tid; f < 4096; f += 256) {
        int j = f & 7, lane = (f >> 3) & 63, nt = (f >> 9) & 3, ks = (f >> 11) & 1;
        int k = ks * 32 + ((lane >> 4) << 2) + (j & 3) + ((j & 4) << 2);
        int n = nt * 16 + (lane & 15);
        w0f[f] = f2bf(W0[k * 64 + n]);
    }
    for (int f = tid; f < 8192; f += 256) {
        int j = f & 7, lane = (f >> 3) & 63, nt = (f >> 9) & 7, ks = (f >> 12) & 1;
        int k = ks * 32 + ((lane >> 4) << 2) + (j & 3) + ((j & 4) << 2);
        int n = nt * 16 + (lane & 15);
        w1f[f] = f2bf(W1[k * 128 + n]);
    }
    __syncthreads();

    const int wv = tid >> 6;
    const int lane = tid & 63;
    const int lm = lane & 15;
    const int lq = lane >> 4;

    float b0r[4], b1r[8];
#pragma unroll
    for (int nt = 0; nt < 4; ++nt) b0r[nt] = b0[nt * 16 + lm];
#pragma unroll
    for (int nt = 0; nt < 8; ++nt) b1r[nt] = b1[nt * 16 + lm];

    const bf16x8* w0v = (const bf16x8*)w0f;
    const bf16x8* w1v = (const bf16x8*)w1f;

    for (int t = 0; t < 4; ++t) {
        const int tile = (blockIdx.x * 4 + wv) * 4 + t;
        const int ebase = tile * 16;

        const f32x4* er = (const f32x4*)(ef + (size_t)(ebase + lm) * D_EDGE);
        f32x4 a0 = er[lq];
        f32x4 a1 = er[4 + lq];
        f32x4 a2 = er[8 + lq];
        f32x4 a3 = er[12 + lq];
        bf16x8 af0, af1;
#pragma unroll
        for (int j = 0; j < 4; ++j) {
            af0[j] = (short)f2bf(a0[j]); af0[j + 4] = (short)f2bf(a1[j]);
            af1[j] = (short)f2bf(a2[j]); af1[j + 4] = (short)f2bf(a3[j]);
        }

        f32x4 h[4];
#pragma unroll
        for (int nt = 0; nt < 4; ++nt) h[nt] = f32x4{0.f, 0.f, 0.f, 0.f};
#pragma unroll
        for (int nt = 0; nt < 4; ++nt) {
            h[nt] = __builtin_amdgcn_mfma_f32_16x16x32_bf16(af0, w0v[(0 * 4 + nt) * 64 + lane], h[nt], 0, 0, 0);
            h[nt] = __builtin_amdgcn_mfma_f32_16x16x32_bf16(af1, w0v[(1 * 4 + nt) * 64 + lane], h[nt], 0, 0, 0);
        }
#pragma unroll
        for (int nt = 0; nt < 4; ++nt)
#pragma unroll
            for (int r = 0; r < 4; ++r) {
                float x = h[nt][r] + b0r[nt];
                hT[wv][lq * 4 + r][nt * 16 + lm] = f2bf(fmaxf(x, 0.f));
            }

        const unsigned short* hrow = &hT[wv][lm][0];
        u16x4 p0 = *(const u16x4*)(hrow + lq * 4);
        u16x4 p1 = *(const u16x4*)(hrow + 16 + lq * 4);
        u16x4 p2 = *(const u16x4*)(hrow + 32 + lq * 4);
        u16x4 p3 = *(const u16x4*)(hrow + 48 + lq * 4);
        bf16x8 g0, g1;
#pragma unroll
        for (int j = 0; j < 4; ++j) {
            g0[j] = (short)p0[j]; g0[j + 4] = (short)p1[j];
            g1[j] = (short)p2[j]; g1[j + 4] = (short)p3[j];
        }

        f32x4 o[8];
#pragma unroll
        for (int nt = 0; nt < 8; ++nt) o[nt] = f32x4{0.f, 0.f, 0.f, 0.f};
#pragma unroll
        for (int nt = 0; nt < 8; ++nt) {
            o[nt] = __builtin_amdgcn_mfma_f32_16x16x32_bf16(g0, w1v[(0 * 8 + nt) * 64 + lane], o[nt], 0, 0, 0);
            o[nt] = __builtin_amdgcn_mfma_f32_16x16x32_bf16(g1, w1v[(1 * 8 + nt) * 64 + lane], o[nt], 0, 0, 0);
        }

        const int e0 = ebase + lq * 4;
        int s_[4], d_[4];
#pragma unroll
        for (int r = 0; r < 4; ++r) { s_[r] = src[e0 + r]; d_[r] = dst[e0 + r]; }
#pragma unroll
        for (int r = 0; r < 4; ++r) {
            const float* nrow = nf + (size_t)s_[r] * D_NODE;
            float* arow = acc + (size_t)d_[r] * D_NODE;
#pragma unroll
            for (int nt = 0; nt < 8; ++nt) {
                float e2 = fmaxf(o[nt][r] + b1r[nt], 0.f);
                float x = e2 + nrow[nt * 16 + lm];
                unsafeAtomicAdd(&arow[nt * 16 + lm], fmaxf(x, 0.f));
            }
        }
    }
}

// =============== kernel: out = acc @ Wa + ba, in place =======================
__global__ __launch_bounds__(256) void k_out(
    const float* __restrict__ Wa, const float* __restrict__ ba,
    float* __restrict__ out)
{
    __shared__ unsigned short waf[4 * 8 * 64 * 8];   // 32 KB

    const int tid = threadIdx.x;
    for (int f = tid; f < 16384; f += 256) {
        int j = f & 7, lane = (f >> 3) & 63, nt = (f >> 9) & 7, ks = (f >> 12) & 3;
        int k = ks * 32 + ((lane >> 4) << 2) + (j & 3) + ((j & 4) << 2);
        int n = nt * 16 + (lane & 15);
        waf[f] = f2bf(Wa[k * 128 + n]);
    }
    __syncthreads();

    const int wv = tid >> 6;
    const int lane = tid & 63;
    const int lm = lane & 15;
    const int lq = lane >> 4;

    const int tile = blockIdx.x * 4 + wv;
    if (tile >= N_NODES / 16) return;
    const int rbase = tile * 16;

    const f32x4* arow = (const f32x4*)(out + (size_t)(rbase + lm) * D_NODE);
    const bf16x8* wav = (const bf16x8*)waf;

    bf16x8 afr[4];
#pragma unroll
    for (int ks = 0; ks < 4; ++ks) {
        f32x4 y0 = arow[ks * 8 + lq];
        f32x4 y1 = arow[ks * 8 + 4 + lq];
#pragma unroll
        for (int j = 0; j < 4; ++j) {
            afr[ks][j] = (short)f2bf(y0[j]);
            afr[ks][j + 4] = (short)f2bf(y1[j]);
        }
    }

    float bar[8];
#pragma unroll
    for (int nt = 0; nt < 8; ++nt) bar[nt] = ba[nt * 16 + lm];

    f32x4 o[8];
#pragma unroll
    for (int nt = 0; nt < 8; ++nt) o[nt] = f32x4{0.f, 0.f, 0.f, 0.f};
#pragma unroll
    for (int ks = 0; ks < 4; ++ks)
#pragma unroll
        for (int nt = 0; nt < 8; ++nt)
            o[nt] = __builtin_amdgcn_mfma_f32_16x16x32_bf16(afr[ks], wav[(ks * 8 + nt) * 64 + lane], o[nt], 0, 0, 0);

#pragma unroll
    for (int nt = 0; nt < 8; ++nt)
#pragma unroll
        for (int r = 0; r < 4; ++r)
            out[(size_t)(rbase + lq * 4 + r) * D_NODE + nt * 16 + lm] = o[nt][r] + bar[nt];
}

extern "C" void kernel_launch(void* const* d_in, const int* in_sizes, int n_in,
                              void* d_out, int out_size, void* d_ws, size_t ws_size,
                              hipStream_t stream) {
    const float* nf = (const float*)d_in[0];
    const float* ef = (const float*)d_in[1];
    const float* W0 = (const float*)d_in[2];
    const float* b0 = (const float*)d_in[3];
    const float* W1 = (const float*)d_in[4];
    const float* b1 = (const float*)d_in[5];
    const float* Wa = (const float*)d_in[6];
    const float* ba = (const float*)d_in[7];
    const int* src = (const int*)d_in[8];
    const int* dst = (const int*)d_in[9];
    float* out = (float*)d_out;

    if (ws_size >= WS_NEED) {
        char* ws = (char*)d_ws;
        int* start = (int*)(ws + START_OFF);
        int* fill  = (int*)(ws + FILL_OFF);
        int4* meta = (int4*)(ws + META_OFF);
        unsigned short* nf16t = (unsigned short*)(ws + NF16_OFF);
        unsigned short* w0frag = (unsigned short*)(ws + W0F_OFF);
        unsigned short* w1frag = (unsigned short*)(ws + W1F_OFF);
        int* bsum  = (int*)(ws + META_OFF);   // scratch reuse before kpos

        const int n_scan = N_NODES + 1;
        const int nb = (n_scan + 255) / 256;   // 196
        const int nprep = (N_NODES + 15) / 16; // 3125

        hipMemsetAsync(start, 0, n_scan * sizeof(int), stream);
        k_prep<<<nprep + 32, 256, 0, stream>>>(nf, out, nf16t, W0, W1, w0frag, w1frag, nprep);

        kh<<<(N_EDGES + 255) / 256, 256, 0, stream>>>(dst, start);
        ks1<<<nb, 256, 0, stream>>>(start, bsum, n_scan);
        ks2<<<1, 256, 0, stream>>>(bsum, nb);
        ks3<<<nb, 256, 0, stream>>>(bsum, start, fill, n_scan);
        kpos<<<(N_EDGES + 255) / 256, 256, 0, stream>>>(dst, src, fill, meta);

        // fused: pipelined edge MLP in CSR order + mT segment reduce
        k_fused<<<N_EDGES / 256, 256, 0, stream>>>(
            ef, nf16t, w0frag, w1frag, b0, b1, meta, out);
    } else {
        k_copy<<<2048, 256, 0, stream>>>((const f32x4*)nf, (f32x4*)out, N_NODES * D_NODE / 4);
        k_edge<<<N_EDGES / (16 * 4 * 4), 256, 0, stream>>>(ef, nf, W0, b0, W1, b1, src, dst, out);
    }

    // out = rst @ Wa + ba (in place)
    k_out<<<(N_NODES / 16 + 3) / 4, 256, 0, stream>>>(Wa, ba, out);
}

// Round 17
// 260.693 us; speedup vs baseline: 1.0832x; 1.0832x over previous
//
#include <hip/hip_runtime.h>

typedef short bf16x8 __attribute__((ext_vector_type(8)));
typedef float f32x4 __attribute__((ext_vector_type(4)));
typedef unsigned short u16x2 __attribute__((ext_vector_type(2)));
typedef unsigned short u16x4 __attribute__((ext_vector_type(4)));
typedef unsigned short u16x8 __attribute__((ext_vector_type(8)));

static constexpr int N_NODES = 50000;
static constexpr int N_EDGES = 800000;
static constexpr int D_NODE = 128;
static constexpr int D_EDGE = 64;

// workspace layout (bytes)
static constexpr size_t START_OFF = 0;                       // (N_NODES+1) ints
static constexpr size_t FILL_OFF  = 262144;                  // N_NODES ints
static constexpr size_t BSUM_OFF  = 462144;                  // 256 ints (scan block sums)
static constexpr size_t META_OFF  = 524288;                  // N_EDGES int4
static constexpr size_t NF16_OFF  = META_OFF + (size_t)N_EDGES * 16;
static constexpr size_t W0F_OFF   = NF16_OFF + (size_t)N_NODES * D_NODE * 2;
static constexpr size_t W1F_OFF   = W0F_OFF + 4096 * 2;
static constexpr size_t WS_NEED   = W1F_OFF + 8192 * 2;

__device__ __forceinline__ unsigned short f2bf(float f) {
    union { float f; unsigned u; } v; v.f = f;
    return (unsigned short)((v.u + 0x7fffu + ((v.u >> 16) & 1u)) >> 16);
}
__device__ __forceinline__ float bf2f(unsigned short h) {
    union { unsigned u; float f; } v; v.u = ((unsigned)h) << 16;
    return v.f;
}

// =============== prep (merged): acc init + nf16t + weight frags + histogram ==
// blocks [0, nprep): per-node copy/transpose. [nprep, nprep+32): wfrag.
// [nprep+32, nprep+32+nhist): dst histogram (start must be pre-zeroed).
__global__ __launch_bounds__(256) void k_prep(const float* __restrict__ nf,
                                              float* __restrict__ out,
                                              unsigned short* __restrict__ nf16t,
                                              const float* __restrict__ W0,
                                              const float* __restrict__ W1,
                                              unsigned short* __restrict__ w0frag,
                                              unsigned short* __restrict__ w1frag,
                                              const int* __restrict__ dst,
                                              int* __restrict__ start,
                                              int nprep) {
    const int b = (int)blockIdx.x;
    if (b >= nprep + 32) {
        // histogram section
        const int e = (b - nprep - 32) * 256 + threadIdx.x;
        if (e < N_EDGES) atomicAdd(&start[dst[e] + 1], 1);
        return;
    }
    if (b >= nprep) {
        const int f = (b - nprep) * 256 + threadIdx.x;   // 0..8191
        if (f < 4096) {
            int j = f & 7, lane = (f >> 3) & 63, nt = (f >> 9) & 3, ks = (f >> 11) & 1;
            int k = ks * 32 + ((lane >> 4) << 2) + (j & 3) + ((j & 4) << 2);
            int n = nt * 16 + (lane & 15);
            w0frag[f] = f2bf(W0[k * 64 + n]);
        }
        if (f < 8192) {
            int j = f & 7, lane = (f >> 3) & 63, nt = (f >> 9) & 7, ks = (f >> 12) & 1;
            int k = ks * 32 + ((lane >> 4) << 2) + (j & 3) + ((j & 4) << 2);
            int n = nt * 16 + (lane & 15);
            w1frag[f] = f2bf(W1[k * 128 + n]);
        }
        return;
    }
    const int tid = threadIdx.x;
    const int lm = tid & 15;
    const int node = b * 16 + (tid >> 4);
    if (node >= N_NODES) return;
    const float* nrow = nf + (size_t)node * D_NODE;
    float* orow = out + (size_t)node * D_NODE;
    f32x4 y0 = *(const f32x4*)(nrow + lm * 8);
    f32x4 y1 = *(const f32x4*)(nrow + lm * 8 + 4);
    *(f32x4*)(orow + lm * 8) = y0;
    *(f32x4*)(orow + lm * 8 + 4) = y1;
    u16x8 tv;
#pragma unroll
    for (int nt = 0; nt < 8; ++nt) tv[nt] = f2bf(nrow[nt * 16 + lm]);
    *(u16x8*)(nf16t + (size_t)node * D_NODE + lm * 8) = tv;
}

// =============== scan step 1: per-256-block sums ==============================
__global__ __launch_bounds__(256) void ks1(const int* __restrict__ a, int* __restrict__ bsum, int n) {
    __shared__ int sd[256];
    const int t = threadIdx.x;
    int i = blockIdx.x * 256 + t;
    sd[t] = (i < n) ? a[i] : 0;
    __syncthreads();
    for (int off = 128; off > 0; off >>= 1) {
        if (t < off) sd[t] += sd[t + off];
        __syncthreads();
    }
    if (t == 0) bsum[blockIdx.x] = sd[0];
}

// =============== scan step 2 (merged): each block self-scans bsum + local ====
__global__ __launch_bounds__(256) void ks3(const int* __restrict__ bsum,
                                           int* __restrict__ start, int* __restrict__ fill,
                                           int n, int nb) {
    __shared__ int sb[256];
    __shared__ int sd[256];
    const int t = threadIdx.x;

    // self-scan of block sums (196 entries) — removes the ks2 dispatch
    sb[t] = (t < nb) ? bsum[t] : 0;
    __syncthreads();
    for (int off = 1; off < 256; off <<= 1) {
        int v = (t >= off) ? sb[t - off] : 0;
        __syncthreads();
        sb[t] += v;
        __syncthreads();
    }

    const int i = blockIdx.x * 256 + t;
    sd[t] = (i < n) ? start[i] : 0;
    __syncthreads();
    for (int off = 1; off < 256; off <<= 1) {
        int v = (t >= off) ? sd[t - off] : 0;
        __syncthreads();
        sd[t] += v;
        __syncthreads();
    }
    const int off0 = (blockIdx.x > 0) ? sb[blockIdx.x - 1] : 0;
    const int val = sd[t] + off0;
    if (i < n) start[i] = val;
    if (i < N_NODES) fill[i] = val;
}

// build CSR order: meta[p] = (edge, src, dst, 0) — one 16B scatter per edge
__global__ void kpos(const int* __restrict__ dst, const int* __restrict__ src,
                     int* __restrict__ fill, int4* __restrict__ meta) {
    int e = blockIdx.x * blockDim.x + threadIdx.x;
    if (e < N_EDGES) {
        int d = dst[e];
        int p = atomicAdd(&fill[d], 1);
        meta[p] = int4{e, src[e], d, 0};
    }
}

// =============== fused: edge MLP (CSR order) + mT segment reduce (r14) =======
// 256 threads, 4 waves, 4 tiles/wave. Weights from GLOBAL (L1-resident, 24KB).
// LDS = hT+mT = 26KB. Plain schedule — r15 (register reduce) and r16
// (tile-ahead prefetch) both regressed; this exact form measured 155us.
// NO min-waves bound (r10/r13: capping below ~85 regs spills to scratch).
__global__ __launch_bounds__(256) void k_fused(
    const float* __restrict__ ef, const unsigned short* __restrict__ nf16t,
    const unsigned short* __restrict__ w0frag, const unsigned short* __restrict__ w1frag,
    const float* __restrict__ b0, const float* __restrict__ b1,
    const int4* __restrict__ meta, float* __restrict__ out)
{
    __shared__ __align__(16) unsigned short hT[4][16][72];    // 9 KB
    __shared__ __align__(16) unsigned short mT[4][16][136];   // 17 KB

    const int tid = threadIdx.x;

    // bijective XCD swizzle (m204): contiguous CSR ranges stay on one XCD
    int bid = blockIdx.x;
    {
        const int nwg = gridDim.x;            // 3125
        const int q = nwg >> 3, rr = nwg & 7; // q=390, rr=5
        const int xcd = bid & 7, j = bid >> 3;
        bid = (xcd < rr ? xcd * (q + 1) : rr * (q + 1) + (xcd - rr) * q) + j;
    }

    const int wv = tid >> 6;
    const int lane = tid & 63;
    const int lm = lane & 15;
    const int lq = lane >> 4;

    float b0r[4], b1r[8];
#pragma unroll
    for (int nt = 0; nt < 4; ++nt) b0r[nt] = b0[nt * 16 + lm];
#pragma unroll
    for (int nt = 0; nt < 8; ++nt) b1r[nt] = b1[nt * 16 + lm];

    const bf16x8* w0v = (const bf16x8*)w0frag;   // global, L1-hit after 1st touch
    const bf16x8* w1v = (const bf16x8*)w1frag;

    const int wtile0 = (bid * 4 + wv) * 4;

    for (int t = 0; t < 4; ++t) {
        const int ebase = (wtile0 + t) * 16;

        // ---- one int4 meta load per lane (edge, src, dst) ----
        const int4 m4 = meta[ebase + lm];
        const int e_m = m4.x, s_m = m4.y, d_m = m4.z;

        // ---- ef row lm ----
        const f32x4* er = (const f32x4*)(ef + (size_t)e_m * D_EDGE);
        f32x4 a0 = er[lq];
        f32x4 a1 = er[4 + lq];
        f32x4 a2 = er[8 + lq];
        f32x4 a3 = er[12 + lq];

        // ---- bf16 node-row gathers (issued early, consumed after MLP) ----
        u16x8 ngb[4];
#pragma unroll
        for (int r = 0; r < 4; ++r) {
            const int s_row = __shfl(s_m, lq * 4 + r);
            ngb[r] = *(const u16x8*)(nf16t + (size_t)s_row * D_NODE + lm * 8);
        }

        bf16x8 af0, af1;
#pragma unroll
        for (int j = 0; j < 4; ++j) {
            af0[j] = (short)f2bf(a0[j]); af0[j + 4] = (short)f2bf(a1[j]);
            af1[j] = (short)f2bf(a2[j]); af1[j + 4] = (short)f2bf(a3[j]);
        }

        // ---- layer 1 ----
        f32x4 h[4];
#pragma unroll
        for (int nt = 0; nt < 4; ++nt) h[nt] = f32x4{0.f, 0.f, 0.f, 0.f};
#pragma unroll
        for (int nt = 0; nt < 4; ++nt) {
            h[nt] = __builtin_amdgcn_mfma_f32_16x16x32_bf16(af0, w0v[(0 * 4 + nt) * 64 + lane], h[nt], 0, 0, 0);
            h[nt] = __builtin_amdgcn_mfma_f32_16x16x32_bf16(af1, w0v[(1 * 4 + nt) * 64 + lane], h[nt], 0, 0, 0);
        }
#pragma unroll
        for (int nt = 0; nt < 4; ++nt)
#pragma unroll
            for (int r = 0; r < 4; ++r) {
                float x = h[nt][r] + b0r[nt];
                hT[wv][lq * 4 + r][nt * 16 + lm] = f2bf(fmaxf(x, 0.f));
            }

        const unsigned short* hrow = &hT[wv][lm][0];
        u16x4 p0 = *(const u16x4*)(hrow + lq * 4);
        u16x4 p1 = *(const u16x4*)(hrow + 16 + lq * 4);
        u16x4 p2 = *(const u16x4*)(hrow + 32 + lq * 4);
        u16x4 p3 = *(const u16x4*)(hrow + 48 + lq * 4);
        bf16x8 g0, g1;
#pragma unroll
        for (int j = 0; j < 4; ++j) {
            g0[j] = (short)p0[j]; g0[j + 4] = (short)p1[j];
            g1[j] = (short)p2[j]; g1[j + 4] = (short)p3[j];
        }

        // ---- layer 2 ----
        f32x4 o[8];
#pragma unroll
        for (int nt = 0; nt < 8; ++nt) o[nt] = f32x4{0.f, 0.f, 0.f, 0.f};
#pragma unroll
        for (int nt = 0; nt < 8; ++nt) {
            o[nt] = __builtin_amdgcn_mfma_f32_16x16x32_bf16(g0, w1v[(0 * 8 + nt) * 64 + lane], o[nt], 0, 0, 0);
            o[nt] = __builtin_amdgcn_mfma_f32_16x16x32_bf16(g1, w1v[(1 * 8 + nt) * 64 + lane], o[nt], 0, 0, 0);
        }

        // ---- combine: e = relu(o+b1); m = relu(x_src + e) -> mT (per-wave) --
#pragma unroll
        for (int nt = 0; nt < 8; ++nt)
#pragma unroll
            for (int r = 0; r < 4; ++r) {
                float e2 = fmaxf(o[nt][r] + b1r[nt], 0.f);
                float x = e2 + bf2f(ngb[r][nt]);
                mT[wv][lq * 4 + r][nt * 16 + lm] = f2bf(fmaxf(x, 0.f));
            }

        // wave-local LDS RAW: drain LDS writes, pin ordering (no block barrier)
        asm volatile("s_waitcnt lgkmcnt(0)" ::: "memory");
        __builtin_amdgcn_sched_barrier(0);

        // ---- inline segment-sum: lane owns cols {lane*2, lane*2+1} ----
        float acc0 = 0.f, acc1 = 0.f;
        int dprev = __shfl(d_m, 0);
#pragma unroll
        for (int r = 0; r < 16; ++r) {
            const int dr = __shfl(d_m, r);
            if (dr != dprev) {                    // wave-uniform condition
                float* orow = out + (size_t)dprev * D_NODE + lane * 2;
                unsafeAtomicAdd(orow, acc0);
                unsafeAtomicAdd(orow + 1, acc1);
                acc0 = 0.f; acc1 = 0.f; dprev = dr;
            }
            const u16x2 v = *(const u16x2*)&mT[wv][r][lane * 2];   // typed load
            acc0 += bf2f(v[0]);
            acc1 += bf2f(v[1]);
        }
        float* orow = out + (size_t)dprev * D_NODE + lane * 2;
        unsafeAtomicAdd(orow, acc0);
        unsafeAtomicAdd(orow + 1, acc1);

        asm volatile("" ::: "memory");   // keep next tile's mT writes below these reads
    }
}

// =============== fallback path (atomic scatter), known-good ==================
__global__ void k_copy(const f32x4* __restrict__ s, f32x4* __restrict__ d, int n4) {
    int stride = gridDim.x * blockDim.x;
    for (int i = blockIdx.x * blockDim.x + threadIdx.x; i < n4; i += stride)
        d[i] = s[i];
}

__global__ __launch_bounds__(256) void k_edge(
    const float* __restrict__ ef, const float* __restrict__ nf,
    const float* __restrict__ W0, const float* __restrict__ b0,
    const float* __restrict__ W1, const float* __restrict__ b1,
    const int* __restrict__ src, const int* __restrict__ dst,
    float* __restrict__ acc)
{
    __shared__ unsigned short w0f[2 * 4 * 64 * 8];
    __shared__ unsigned short w1f[2 * 8 * 64 * 8];
    __shared__ unsigned short hT[4][16][72];

    const int tid = threadIdx.x;
    for (int f = tid; f < 4096; f += 256) {
        int j = f & 7, lane = (f >> 3) & 63, nt = (f >> 9) & 3, ks = (f >> 11) & 1;
        int k = ks * 32 + ((lane >> 4) << 2) + (j & 3) + ((j & 4) << 2);
        int n = nt * 16 + (lane & 15);
        w0f[f] = f2bf(W0[k * 64 + n]);
    }
    for (int f = tid; f < 8192; f += 256) {
        int j = f & 7, lane = (f >> 3) & 63, nt = (f >> 9) & 7, ks = (f >> 12) & 1;
        int k = ks * 32 + ((lane >> 4) << 2) + (j & 3) + ((j & 4) << 2);
        int n = nt * 16 + (lane & 15);
        w1f[f] = f2bf(W1[k * 128 + n]);
    }
    __syncthreads();

    const int wv = tid >> 6;
    const int lane = tid & 63;
    const int lm = lane & 15;
    const int lq = lane >> 4;

    float b0r[4], b1r[8];
#pragma unroll
    for (int nt = 0; nt < 4; ++nt) b0r[nt] = b0[nt * 16 + lm];
#pragma unroll
    for (int nt = 0; nt < 8; ++nt) b1r[nt] = b1[nt * 16 + lm];

    const bf16x8* w0v = (const bf16x8*)w0f;
    const bf16x8* w1v = (const bf16x8*)w1f;

    for (int t = 0; t < 4; ++t) {
        const int tile = (blockIdx.x * 4 + wv) * 4 + t;
        const int ebase = tile * 16;

        const f32x4* er = (const f32x4*)(ef + (size_t)(ebase + lm) * D_EDGE);
        f32x4 a0 = er[lq];
        f32x4 a1 = er[4 + lq];
        f32x4 a2 = er[8 + lq];
        f32x4 a3 = er[12 + lq];
        bf16x8 af0, af1;
#pragma unroll
        for (int j = 0; j < 4; ++j) {
            af0[j] = (short)f2bf(a0[j]); af0[j + 4] = (short)f2bf(a1[j]);
            af1[j] = (short)f2bf(a2[j]); af1[j + 4] = (short)f2bf(a3[j]);
        }

        f32x4 h[4];
#pragma unroll
        for (int nt = 0; nt < 4; ++nt) h[nt] = f32x4{0.f, 0.f, 0.f, 0.f};
#pragma unroll
        for (int nt = 0; nt < 4; ++nt) {
            h[nt] = __builtin_amdgcn_mfma_f32_16x16x32_bf16(af0, w0v[(0 * 4 + nt) * 64 + lane], h[nt], 0, 0, 0);
            h[nt] = __builtin_amdgcn_mfma_f32_16x16x32_bf16(af1, w0v[(1 * 4 + nt) * 64 + lane], h[nt], 0, 0, 0);
        }
#pragma unroll
        for (int nt = 0; nt < 4; ++nt)
#pragma unroll
            for (int r = 0; r < 4; ++r) {
                float x = h[nt][r] + b0r[nt];
                hT[wv][lq * 4 + r][nt * 16 + lm] = f2bf(fmaxf(x, 0.f));
            }

        const unsigned short* hrow = &hT[wv][lm][0];
        u16x4 p0 = *(const u16x4*)(hrow + lq * 4);
        u16x4 p1 = *(const u16x4*)(hrow + 16 + lq * 4);
        u16x4 p2 = *(const u16x4*)(hrow + 32 + lq * 4);
        u16x4 p3 = *(const u16x4*)(hrow + 48 + lq * 4);
        bf16x8 g0, g1;
#pragma unroll
        for (int j = 0; j < 4; ++j) {
            g0[j] = (short)p0[j]; g0[j + 4] = (short)p1[j];
            g1[j] = (short)p2[j]; g1[j + 4] = (short)p3[j];
        }

        f32x4 o[8];
#pragma unroll
        for (int nt = 0; nt < 8; ++nt) o[nt] = f32x4{0.f, 0.f, 0.f, 0.f};
#pragma unroll
        for (int nt = 0; nt < 8; ++nt) {
            o[nt] = __builtin_amdgcn_mfma_f32_16x16x32_bf16(g0, w1v[(0 * 8 + nt) * 64 + lane], o[nt], 0, 0, 0);
            o[nt] = __builtin_amdgcn_mfma_f32_16x16x32_bf16(g1, w1v[(1 * 8 + nt) * 64 + lane], o[nt], 0, 0, 0);
        }

        const int e0 = ebase + lq * 4;
        int s_[4], d_[4];
#pragma unroll
        for (int r = 0; r < 4; ++r) { s_[r] = src[e0 + r]; d_[r] = dst[e0 + r]; }
#pragma unroll
        for (int r = 0; r < 4; ++r) {
            const float* nrow = nf + (size_t)s_[r] * D_NODE;
            float* arow = acc + (size_t)d_[r] * D_NODE;
#pragma unroll
            for (int nt = 0; nt < 8; ++nt) {
                float e2 = fmaxf(o[nt][r] + b1r[nt], 0.f);
                float x = e2 + nrow[nt * 16 + lm];
                unsafeAtomicAdd(&arow[nt * 16 + lm], fmaxf(x, 0.f));
            }
        }
    }
}

// =============== kernel: out = acc @ Wa + ba, in place =======================
__global__ __launch_bounds__(256) void k_out(
    const float* __restrict__ Wa, const float* __restrict__ ba,
    float* __restrict__ out)
{
    __shared__ unsigned short waf[4 * 8 * 64 * 8];   // 32 KB

    const int tid = threadIdx.x;
    for (int f = tid; f < 16384; f += 256) {
        int j = f & 7, lane = (f >> 3) & 63, nt = (f >> 9) & 7, ks = (f >> 12) & 3;
        int k = ks * 32 + ((lane >> 4) << 2) + (j & 3) + ((j & 4) << 2);
        int n = nt * 16 + (lane & 15);
        waf[f] = f2bf(Wa[k * 128 + n]);
    }
    __syncthreads();

    const int wv = tid >> 6;
    const int lane = tid & 63;
    const int lm = lane & 15;
    const int lq = lane >> 4;

    const int tile = blockIdx.x * 4 + wv;
    if (tile >= N_NODES / 16) return;
    const int rbase = tile * 16;

    const f32x4* arow = (const f32x4*)(out + (size_t)(rbase + lm) * D_NODE);
    const bf16x8* wav = (const bf16x8*)waf;

    bf16x8 afr[4];
#pragma unroll
    for (int ks = 0; ks < 4; ++ks) {
        f32x4 y0 = arow[ks * 8 + lq];
        f32x4 y1 = arow[ks * 8 + 4 + lq];
#pragma unroll
        for (int j = 0; j < 4; ++j) {
            afr[ks][j] = (short)f2bf(y0[j]);
            afr[ks][j + 4] = (short)f2bf(y1[j]);
        }
    }

    float bar[8];
#pragma unroll
    for (int nt = 0; nt < 8; ++nt) bar[nt] = ba[nt * 16 + lm];

    f32x4 o[8];
#pragma unroll
    for (int nt = 0; nt < 8; ++nt) o[nt] = f32x4{0.f, 0.f, 0.f, 0.f};
#pragma unroll
    for (int ks = 0; ks < 4; ++ks)
#pragma unroll
        for (int nt = 0; nt < 8; ++nt)
            o[nt] = __builtin_amdgcn_mfma_f32_16x16x32_bf16(afr[ks], wav[(ks * 8 + nt) * 64 + lane], o[nt], 0, 0, 0);

#pragma unroll
    for (int nt = 0; nt < 8; ++nt)
#pragma unroll
        for (int r = 0; r < 4; ++r)
            out[(size_t)(rbase + lq * 4 + r) * D_NODE + nt * 16 + lm] = o[nt][r] + bar[nt];
}

extern "C" void kernel_launch(void* const* d_in, const int* in_sizes, int n_in,
                              void* d_out, int out_size, void* d_ws, size_t ws_size,
                              hipStream_t stream) {
    const float* nf = (const float*)d_in[0];
    const float* ef = (const float*)d_in[1];
    const float* W0 = (const float*)d_in[2];
    const float* b0 = (const float*)d_in[3];
    const float* W1 = (const float*)d_in[4];
    const float* b1 = (const float*)d_in[5];
    const float* Wa = (const float*)d_in[6];
    const float* ba = (const float*)d_in[7];
    const int* src = (const int*)d_in[8];
    const int* dst = (const int*)d_in[9];
    float* out = (float*)d_out;

    if (ws_size >= WS_NEED) {
        char* ws = (char*)d_ws;
        int* start = (int*)(ws + START_OFF);
        int* fill  = (int*)(ws + FILL_OFF);
        int* bsum  = (int*)(ws + BSUM_OFF);
        int4* meta = (int4*)(ws + META_OFF);
        unsigned short* nf16t = (unsigned short*)(ws + NF16_OFF);
        unsigned short* w0frag = (unsigned short*)(ws + W0F_OFF);
        unsigned short* w1frag = (unsigned short*)(ws + W1F_OFF);

        const int n_scan = N_NODES + 1;
        const int nb = (n_scan + 255) / 256;          // 196
        const int nprep = (N_NODES + 15) / 16;        // 3125
        const int nhist = (N_EDGES + 255) / 256;      // 3125

        hipMemsetAsync(start, 0, n_scan * sizeof(int), stream);

        // merged: acc init + nf16t transpose + weight frags + dst histogram
        k_prep<<<nprep + 32 + nhist, 256, 0, stream>>>(
            nf, out, nf16t, W0, W1, w0frag, w1frag, dst, start, nprep);

        ks1<<<nb, 256, 0, stream>>>(start, bsum, n_scan);
        ks3<<<nb, 256, 0, stream>>>(bsum, start, fill, n_scan, nb);
        kpos<<<(N_EDGES + 255) / 256, 256, 0, stream>>>(dst, src, fill, meta);

        // fused: edge MLP in CSR order + mT segment reduce (r14 form)
        k_fused<<<N_EDGES / 256, 256, 0, stream>>>(
            ef, nf16t, w0frag, w1frag, b0, b1, meta, out);
    } else {
        k_copy<<<2048, 256, 0, stream>>>((const f32x4*)nf, (f32x4*)out, N_NODES * D_NODE / 4);
        k_edge<<<N_EDGES / (16 * 4 * 4), 256, 0, stream>>>(ef, nf, W0, b0, W1, b1, src, dst, out);
    }

    // out = rst @ Wa + ba (in place)
    k_out<<<(N_NODES / 16 + 3) / 4, 256, 0, stream>>>(Wa, ba, out);
}

// Round 18
// 260.126 us; speedup vs baseline: 1.0856x; 1.0022x over previous
//
#include <hip/hip_runtime.h>

typedef short bf16x8 __attribute__((ext_vector_type(8)));
typedef float f32x4 __attribute__((ext_vector_type(4)));
typedef unsigned short u16x2 __attribute__((ext_vector_type(2)));
typedef unsigned short u16x4 __attribute__((ext_vector_type(4)));
typedef unsigned short u16x8 __attribute__((ext_vector_type(8)));

static constexpr int N_NODES = 50000;
static constexpr int N_EDGES = 800000;
static constexpr int D_NODE = 128;
static constexpr int D_EDGE = 64;

// workspace layout (bytes)
static constexpr size_t START_OFF = 0;                       // (N_NODES+1) ints
static constexpr size_t FILL_OFF  = 262144;                  // N_NODES ints
static constexpr size_t BSUM_OFF  = 462144;                  // 256 ints (scan block sums)
static constexpr size_t META_OFF  = 524288;                  // N_EDGES int4
static constexpr size_t NF16_OFF  = META_OFF + (size_t)N_EDGES * 16;
static constexpr size_t W0F_OFF   = NF16_OFF + (size_t)N_NODES * D_NODE * 2;
static constexpr size_t W1F_OFF   = W0F_OFF + 4096 * 2;
static constexpr size_t WS_NEED   = W1F_OFF + 8192 * 2;

__device__ __forceinline__ unsigned short f2bf(float f) {
    union { float f; unsigned u; } v; v.f = f;
    return (unsigned short)((v.u + 0x7fffu + ((v.u >> 16) & 1u)) >> 16);
}
__device__ __forceinline__ float bf2f(unsigned short h) {
    union { unsigned u; float f; } v; v.u = ((unsigned)h) << 16;
    return v.f;
}

// =============== prep (merged): acc init + nf16t + weight frags + histogram ==
__global__ __launch_bounds__(256) void k_prep(const float* __restrict__ nf,
                                              float* __restrict__ out,
                                              unsigned short* __restrict__ nf16t,
                                              const float* __restrict__ W0,
                                              const float* __restrict__ W1,
                                              unsigned short* __restrict__ w0frag,
                                              unsigned short* __restrict__ w1frag,
                                              const int* __restrict__ dst,
                                              int* __restrict__ start,
                                              int nprep) {
    const int b = (int)blockIdx.x;
    if (b >= nprep + 32) {
        const int e = (b - nprep - 32) * 256 + threadIdx.x;
        if (e < N_EDGES) atomicAdd(&start[dst[e] + 1], 1);
        return;
    }
    if (b >= nprep) {
        const int f = (b - nprep) * 256 + threadIdx.x;   // 0..8191
        if (f < 4096) {
            int j = f & 7, lane = (f >> 3) & 63, nt = (f >> 9) & 3, ks = (f >> 11) & 1;
            int k = ks * 32 + ((lane >> 4) << 2) + (j & 3) + ((j & 4) << 2);
            int n = nt * 16 + (lane & 15);
            w0frag[f] = f2bf(W0[k * 64 + n]);
        }
        if (f < 8192) {
            int j = f & 7, lane = (f >> 3) & 63, nt = (f >> 9) & 7, ks = (f >> 12) & 1;
            int k = ks * 32 + ((lane >> 4) << 2) + (j & 3) + ((j & 4) << 2);
            int n = nt * 16 + (lane & 15);
            w1frag[f] = f2bf(W1[k * 128 + n]);
        }
        return;
    }
    const int tid = threadIdx.x;
    const int lm = tid & 15;
    const int node = b * 16 + (tid >> 4);
    if (node >= N_NODES) return;
    const float* nrow = nf + (size_t)node * D_NODE;
    float* orow = out + (size_t)node * D_NODE;
    f32x4 y0 = *(const f32x4*)(nrow + lm * 8);
    f32x4 y1 = *(const f32x4*)(nrow + lm * 8 + 4);
    *(f32x4*)(orow + lm * 8) = y0;
    *(f32x4*)(orow + lm * 8 + 4) = y1;
    u16x8 tv;
#pragma unroll
    for (int nt = 0; nt < 8; ++nt) tv[nt] = f2bf(nrow[nt * 16 + lm]);
    *(u16x8*)(nf16t + (size_t)node * D_NODE + lm * 8) = tv;
}

// =============== scan step 1: per-256-block sums ==============================
__global__ __launch_bounds__(256) void ks1(const int* __restrict__ a, int* __restrict__ bsum, int n) {
    __shared__ int sd[256];
    const int t = threadIdx.x;
    int i = blockIdx.x * 256 + t;
    sd[t] = (i < n) ? a[i] : 0;
    __syncthreads();
    for (int off = 128; off > 0; off >>= 1) {
        if (t < off) sd[t] += sd[t + off];
        __syncthreads();
    }
    if (t == 0) bsum[blockIdx.x] = sd[0];
}

// =============== scan step 2 (merged): each block self-scans bsum + local ====
__global__ __launch_bounds__(256) void ks3(const int* __restrict__ bsum,
                                           int* __restrict__ start, int* __restrict__ fill,
                                           int n, int nb) {
    __shared__ int sb[256];
    __shared__ int sd[256];
    const int t = threadIdx.x;

    sb[t] = (t < nb) ? bsum[t] : 0;
    __syncthreads();
    for (int off = 1; off < 256; off <<= 1) {
        int v = (t >= off) ? sb[t - off] : 0;
        __syncthreads();
        sb[t] += v;
        __syncthreads();
    }

    const int i = blockIdx.x * 256 + t;
    sd[t] = (i < n) ? start[i] : 0;
    __syncthreads();
    for (int off = 1; off < 256; off <<= 1) {
        int v = (t >= off) ? sd[t - off] : 0;
        __syncthreads();
        sd[t] += v;
        __syncthreads();
    }
    const int off0 = (blockIdx.x > 0) ? sb[blockIdx.x - 1] : 0;
    const int val = sd[t] + off0;
    if (i < n) start[i] = val;
    if (i < N_NODES) fill[i] = val;
}

// build CSR order: meta[p] = (edge, src, dst, 0) — one 16B scatter per edge
__global__ void kpos(const int* __restrict__ dst, const int* __restrict__ src,
                     int* __restrict__ fill, int4* __restrict__ meta) {
    int e = blockIdx.x * blockDim.x + threadIdx.x;
    if (e < N_EDGES) {
        int d = dst[e];
        int p = atomicAdd(&fill[d], 1);
        meta[p] = int4{e, src[e], d, 0};
    }
}

// =============== fused: edge MLP (CSR order) + mT segment reduce =============
// r17 form, ONE change: the segment accumulator (dprev, acc0, acc1) is carried
// ACROSS the wave's 4 tiles (64 contiguous CSR edges). Nodes straddling tile
// boundaries no longer cause an extra flush -> ~45% fewer atomics.
__global__ __launch_bounds__(256) void k_fused(
    const float* __restrict__ ef, const unsigned short* __restrict__ nf16t,
    const unsigned short* __restrict__ w0frag, const unsigned short* __restrict__ w1frag,
    const float* __restrict__ b0, const float* __restrict__ b1,
    const int4* __restrict__ meta, float* __restrict__ out)
{
    __shared__ __align__(16) unsigned short hT[4][16][72];    // 9 KB
    __shared__ __align__(16) unsigned short mT[4][16][136];   // 17 KB

    const int tid = threadIdx.x;

    // bijective XCD swizzle (m204): contiguous CSR ranges stay on one XCD
    int bid = blockIdx.x;
    {
        const int nwg = gridDim.x;            // 3125
        const int q = nwg >> 3, rr = nwg & 7; // q=390, rr=5
        const int xcd = bid & 7, j = bid >> 3;
        bid = (xcd < rr ? xcd * (q + 1) : rr * (q + 1) + (xcd - rr) * q) + j;
    }

    const int wv = tid >> 6;
    const int lane = tid & 63;
    const int lm = lane & 15;
    const int lq = lane >> 4;

    float b0r[4], b1r[8];
#pragma unroll
    for (int nt = 0; nt < 4; ++nt) b0r[nt] = b0[nt * 16 + lm];
#pragma unroll
    for (int nt = 0; nt < 8; ++nt) b1r[nt] = b1[nt * 16 + lm];

    const bf16x8* w0v = (const bf16x8*)w0frag;   // global, L1-hit after 1st touch
    const bf16x8* w1v = (const bf16x8*)w1frag;

    const int wtile0 = (bid * 4 + wv) * 4;

    // segment accumulator carried across the wave's 4 tiles
    float acc0 = 0.f, acc1 = 0.f;
    int dprev = 0;

    for (int t = 0; t < 4; ++t) {
        const int ebase = (wtile0 + t) * 16;

        // ---- one int4 meta load per lane (edge, src, dst) ----
        const int4 m4 = meta[ebase + lm];
        const int e_m = m4.x, s_m = m4.y, d_m = m4.z;

        // ---- ef row lm ----
        const f32x4* er = (const f32x4*)(ef + (size_t)e_m * D_EDGE);
        f32x4 a0 = er[lq];
        f32x4 a1 = er[4 + lq];
        f32x4 a2 = er[8 + lq];
        f32x4 a3 = er[12 + lq];

        // ---- bf16 node-row gathers (issued early, consumed after MLP) ----
        u16x8 ngb[4];
#pragma unroll
        for (int r = 0; r < 4; ++r) {
            const int s_row = __shfl(s_m, lq * 4 + r);
            ngb[r] = *(const u16x8*)(nf16t + (size_t)s_row * D_NODE + lm * 8);
        }

        bf16x8 af0, af1;
#pragma unroll
        for (int j = 0; j < 4; ++j) {
            af0[j] = (short)f2bf(a0[j]); af0[j + 4] = (short)f2bf(a1[j]);
            af1[j] = (short)f2bf(a2[j]); af1[j + 4] = (short)f2bf(a3[j]);
        }

        // ---- layer 1 ----
        f32x4 h[4];
#pragma unroll
        for (int nt = 0; nt < 4; ++nt) h[nt] = f32x4{0.f, 0.f, 0.f, 0.f};
#pragma unroll
        for (int nt = 0; nt < 4; ++nt) {
            h[nt] = __builtin_amdgcn_mfma_f32_16x16x32_bf16(af0, w0v[(0 * 4 + nt) * 64 + lane], h[nt], 0, 0, 0);
            h[nt] = __builtin_amdgcn_mfma_f32_16x16x32_bf16(af1, w0v[(1 * 4 + nt) * 64 + lane], h[nt], 0, 0, 0);
        }
#pragma unroll
        for (int nt = 0; nt < 4; ++nt)
#pragma unroll
            for (int r = 0; r < 4; ++r) {
                float x = h[nt][r] + b0r[nt];
                hT[wv][lq * 4 + r][nt * 16 + lm] = f2bf(fmaxf(x, 0.f));
            }

        const unsigned short* hrow = &hT[wv][lm][0];
        u16x4 p0 = *(const u16x4*)(hrow + lq * 4);
        u16x4 p1 = *(const u16x4*)(hrow + 16 + lq * 4);
        u16x4 p2 = *(const u16x4*)(hrow + 32 + lq * 4);
        u16x4 p3 = *(const u16x4*)(hrow + 48 + lq * 4);
        bf16x8 g0, g1;
#pragma unroll
        for (int j = 0; j < 4; ++j) {
            g0[j] = (short)p0[j]; g0[j + 4] = (short)p1[j];
            g1[j] = (short)p2[j]; g1[j + 4] = (short)p3[j];
        }

        // ---- layer 2 ----
        f32x4 o[8];
#pragma unroll
        for (int nt = 0; nt < 8; ++nt) o[nt] = f32x4{0.f, 0.f, 0.f, 0.f};
#pragma unroll
        for (int nt = 0; nt < 8; ++nt) {
            o[nt] = __builtin_amdgcn_mfma_f32_16x16x32_bf16(g0, w1v[(0 * 8 + nt) * 64 + lane], o[nt], 0, 0, 0);
            o[nt] = __builtin_amdgcn_mfma_f32_16x16x32_bf16(g1, w1v[(1 * 8 + nt) * 64 + lane], o[nt], 0, 0, 0);
        }

        // ---- combine: e = relu(o+b1); m = relu(x_src + e) -> mT (per-wave) --
#pragma unroll
        for (int nt = 0; nt < 8; ++nt)
#pragma unroll
            for (int r = 0; r < 4; ++r) {
                float e2 = fmaxf(o[nt][r] + b1r[nt], 0.f);
                float x = e2 + bf2f(ngb[r][nt]);
                mT[wv][lq * 4 + r][nt * 16 + lm] = f2bf(fmaxf(x, 0.f));
            }

        // wave-local LDS RAW: drain LDS writes, pin ordering (no block barrier)
        asm volatile("s_waitcnt lgkmcnt(0)" ::: "memory");
        __builtin_amdgcn_sched_barrier(0);

        // ---- segment-sum, accumulator carried across tiles ----
        if (t == 0) dprev = __shfl(d_m, 0);
#pragma unroll
        for (int r = 0; r < 16; ++r) {
            const int dr = __shfl(d_m, r);
            if (dr != dprev) {                    // wave-uniform condition
                float* orow = out + (size_t)dprev * D_NODE + lane * 2;
                unsafeAtomicAdd(orow, acc0);
                unsafeAtomicAdd(orow + 1, acc1);
                acc0 = 0.f; acc1 = 0.f; dprev = dr;
            }
            const u16x2 v = *(const u16x2*)&mT[wv][r][lane * 2];   // typed load
            acc0 += bf2f(v[0]);
            acc1 += bf2f(v[1]);
        }
        // NO per-tile flush — state carries into the next tile's CSR range

        asm volatile("" ::: "memory");   // keep next tile's mT writes below these reads
    }

    // final flush for the wave's last open segment
    {
        float* orow = out + (size_t)dprev * D_NODE + lane * 2;
        unsafeAtomicAdd(orow, acc0);
        unsafeAtomicAdd(orow + 1, acc1);
    }
}

// =============== fallback path (atomic scatter), known-good ==================
__global__ void k_copy(const f32x4* __restrict__ s, f32x4* __restrict__ d, int n4) {
    int stride = gridDim.x * blockDim.x;
    for (int i = blockIdx.x * blockDim.x + threadIdx.x; i < n4; i += stride)
        d[i] = s[i];
}

__global__ __launch_bounds__(256) void k_edge(
    const float* __restrict__ ef, const float* __restrict__ nf,
    const float* __restrict__ W0, const float* __restrict__ b0,
    const float* __restrict__ W1, const float* __restrict__ b1,
    const int* __restrict__ src, const int* __restrict__ dst,
    float* __restrict__ acc)
{
    __shared__ unsigned short w0f[2 * 4 * 64 * 8];
    __shared__ unsigned short w1f[2 * 8 * 64 * 8];
    __shared__ unsigned short hT[4][16][72];

    const int tid = threadIdx.x;
    for (int f = tid; f < 4096; f += 256) {
        int j = f & 7, lane = (f >> 3) & 63, nt = (f >> 9) & 3, ks = (f >> 11) & 1;
        int k = ks * 32 + ((lane >> 4) << 2) + (j & 3) + ((j & 4) << 2);
        int n = nt * 16 + (lane & 15);
        w0f[f] = f2bf(W0[k * 64 + n]);
    }
    for (int f = tid; f < 8192; f += 256) {
        int j = f & 7, lane = (f >> 3) & 63, nt = (f >> 9) & 7, ks = (f >> 12) & 1;
        int k = ks * 32 + ((lane >> 4) << 2) + (j & 3) + ((j & 4) << 2);
        int n = nt * 16 + (lane & 15);
        w1f[f] = f2bf(W1[k * 128 + n]);
    }
    __syncthreads();

    const int wv = tid >> 6;
    const int lane = tid & 63;
    const int lm = lane & 15;
    const int lq = lane >> 4;

    float b0r[4], b1r[8];
#pragma unroll
    for (int nt = 0; nt < 4; ++nt) b0r[nt] = b0[nt * 16 + lm];
#pragma unroll
    for (int nt = 0; nt < 8; ++nt) b1r[nt] = b1[nt * 16 + lm];

    const bf16x8* w0v = (const bf16x8*)w0f;
    const bf16x8* w1v = (const bf16x8*)w1f;

    for (int t = 0; t < 4; ++t) {
        const int tile = (blockIdx.x * 4 + wv) * 4 + t;
        const int ebase = tile * 16;

        const f32x4* er = (const f32x4*)(ef + (size_t)(ebase + lm) * D_EDGE);
        f32x4 a0 = er[lq];
        f32x4 a1 = er[4 + lq];
        f32x4 a2 = er[8 + lq];
        f32x4 a3 = er[12 + lq];
        bf16x8 af0, af1;
#pragma unroll
        for (int j = 0; j < 4; ++j) {
            af0[j] = (short)f2bf(a0[j]); af0[j + 4] = (short)f2bf(a1[j]);
            af1[j] = (short)f2bf(a2[j]); af1[j + 4] = (short)f2bf(a3[j]);
        }

        f32x4 h[4];
#pragma unroll
        for (int nt = 0; nt < 4; ++nt) h[nt] = f32x4{0.f, 0.f, 0.f, 0.f};
#pragma unroll
        for (int nt = 0; nt < 4; ++nt) {
            h[nt] = __builtin_amdgcn_mfma_f32_16x16x32_bf16(af0, w0v[(0 * 4 + nt) * 64 + lane], h[nt], 0, 0, 0);
            h[nt] = __builtin_amdgcn_mfma_f32_16x16x32_bf16(af1, w0v[(1 * 4 + nt) * 64 + lane], h[nt], 0, 0, 0);
        }
#pragma unroll
        for (int nt = 0; nt < 4; ++nt)
#pragma unroll
            for (int r = 0; r < 4; ++r) {
                float x = h[nt][r] + b0r[nt];
                hT[wv][lq * 4 + r][nt * 16 + lm] = f2bf(fmaxf(x, 0.f));
            }

        const unsigned short* hrow = &hT[wv][lm][0];
        u16x4 p0 = *(const u16x4*)(hrow + lq * 4);
        u16x4 p1 = *(const u16x4*)(hrow + 16 + lq * 4);
        u16x4 p2 = *(const u16x4*)(hrow + 32 + lq * 4);
        u16x4 p3 = *(const u16x4*)(hrow + 48 + lq * 4);
        bf16x8 g0, g1;
#pragma unroll
        for (int j = 0; j < 4; ++j) {
            g0[j] = (short)p0[j]; g0[j + 4] = (short)p1[j];
            g1[j] = (short)p2[j]; g1[j + 4] = (short)p3[j];
        }

        f32x4 o[8];
#pragma unroll
        for (int nt = 0; nt < 8; ++nt) o[nt] = f32x4{0.f, 0.f, 0.f, 0.f};
#pragma unroll
        for (int nt = 0; nt < 8; ++nt) {
            o[nt] = __builtin_amdgcn_mfma_f32_16x16x32_bf16(g0, w1v[(0 * 8 + nt) * 64 + lane], o[nt], 0, 0, 0);
            o[nt] = __builtin_amdgcn_mfma_f32_16x16x32_bf16(g1, w1v[(1 * 8 + nt) * 64 + lane], o[nt], 0, 0, 0);
        }

        const int e0 = ebase + lq * 4;
        int s_[4], d_[4];
#pragma unroll
        for (int r = 0; r < 4; ++r) { s_[r] = src[e0 + r]; d_[r] = dst[e0 + r]; }
#pragma unroll
        for (int r = 0; r < 4; ++r) {
            const float* nrow = nf + (size_t)s_[r] * D_NODE;
            float* arow = acc + (size_t)d_[r] * D_NODE;
#pragma unroll
            for (int nt = 0; nt < 8; ++nt) {
                float e2 = fmaxf(o[nt][r] + b1r[nt], 0.f);
                float x = e2 + nrow[nt * 16 + lm];
                unsafeAtomicAdd(&arow[nt * 16 + lm], fmaxf(x, 0.f));
            }
        }
    }
}

// =============== kernel: out = acc @ Wa + ba, in place =======================
__global__ __launch_bounds__(256) void k_out(
    const float* __restrict__ Wa, const float* __restrict__ ba,
    float* __restrict__ out)
{
    __shared__ unsigned short waf[4 * 8 * 64 * 8];   // 32 KB

    const int tid = threadIdx.x;
    for (int f = tid; f < 16384; f += 256) {
        int j = f & 7, lane = (f >> 3) & 63, nt = (f >> 9) & 7, ks = (f >> 12) & 3;
        int k = ks * 32 + ((lane >> 4) << 2) + (j & 3) + ((j & 4) << 2);
        int n = nt * 16 + (lane & 15);
        waf[f] = f2bf(Wa[k * 128 + n]);
    }
    __syncthreads();

    const int wv = tid >> 6;
    const int lane = tid & 63;
    const int lm = lane & 15;
    const int lq = lane >> 4;

    const int tile = blockIdx.x * 4 + wv;
    if (tile >= N_NODES / 16) return;
    const int rbase = tile * 16;

    const f32x4* arow = (const f32x4*)(out + (size_t)(rbase + lm) * D_NODE);
    const bf16x8* wav = (const bf16x8*)waf;

    bf16x8 afr[4];
#pragma unroll
    for (int ks = 0; ks < 4; ++ks) {
        f32x4 y0 = arow[ks * 8 + lq];
        f32x4 y1 = arow[ks * 8 + 4 + lq];
#pragma unroll
        for (int j = 0; j < 4; ++j) {
            afr[ks][j] = (short)f2bf(y0[j]);
            afr[ks][j + 4] = (short)f2bf(y1[j]);
        }
    }

    float bar[8];
#pragma unroll
    for (int nt = 0; nt < 8; ++nt) bar[nt] = ba[nt * 16 + lm];

    f32x4 o[8];
#pragma unroll
    for (int nt = 0; nt < 8; ++nt) o[nt] = f32x4{0.f, 0.f, 0.f, 0.f};
#pragma unroll
    for (int ks = 0; ks < 4; ++ks)
#pragma unroll
        for (int nt = 0; nt < 8; ++nt)
            o[nt] = __builtin_amdgcn_mfma_f32_16x16x32_bf16(afr[ks], wav[(ks * 8 + nt) * 64 + lane], o[nt], 0, 0, 0);

#pragma unroll
    for (int nt = 0; nt < 8; ++nt)
#pragma unroll
        for (int r = 0; r < 4; ++r)
            out[(size_t)(rbase + lq * 4 + r) * D_NODE + nt * 16 + lm] = o[nt][r] + bar[nt];
}

extern "C" void kernel_launch(void* const* d_in, const int* in_sizes, int n_in,
                              void* d_out, int out_size, void* d_ws, size_t ws_size,
                              hipStream_t stream) {
    const float* nf = (const float*)d_in[0];
    const float* ef = (const float*)d_in[1];
    const float* W0 = (const float*)d_in[2];
    const float* b0 = (const float*)d_in[3];
    const float* W1 = (const float*)d_in[4];
    const float* b1 = (const float*)d_in[5];
    const float* Wa = (const float*)d_in[6];
    const float* ba = (const float*)d_in[7];
    const int* src = (const int*)d_in[8];
    const int* dst = (const int*)d_in[9];
    float* out = (float*)d_out;

    if (ws_size >= WS_NEED) {
        char* ws = (char*)d_ws;
        int* start = (int*)(ws + START_OFF);
        int* fill  = (int*)(ws + FILL_OFF);
        int* bsum  = (int*)(ws + BSUM_OFF);
        int4* meta = (int4*)(ws + META_OFF);
        unsigned short* nf16t = (unsigned short*)(ws + NF16_OFF);
        unsigned short* w0frag = (unsigned short*)(ws + W0F_OFF);
        unsigned short* w1frag = (unsigned short*)(ws + W1F_OFF);

        const int n_scan = N_NODES + 1;
        const int nb = (n_scan + 255) / 256;          // 196
        const int nprep = (N_NODES + 15) / 16;        // 3125
        const int nhist = (N_EDGES + 255) / 256;      // 3125

        hipMemsetAsync(start, 0, n_scan * sizeof(int), stream);

        // merged: acc init + nf16t transpose + weight frags + dst histogram
        k_prep<<<nprep + 32 + nhist, 256, 0, stream>>>(
            nf, out, nf16t, W0, W1, w0frag, w1frag, dst, start, nprep);

        ks1<<<nb, 256, 0, stream>>>(start, bsum, n_scan);
        ks3<<<nb, 256, 0, stream>>>(bsum, start, fill, n_scan, nb);
        kpos<<<(N_EDGES + 255) / 256, 256, 0, stream>>>(dst, src, fill, meta);

        // fused: edge MLP in CSR order + cross-tile carried segment reduce
        k_fused<<<N_EDGES / 256, 256, 0, stream>>>(
            ef, nf16t, w0frag, w1frag, b0, b1, meta, out);
    } else {
        k_copy<<<2048, 256, 0, stream>>>((const f32x4*)nf, (f32x4*)out, N_NODES * D_NODE / 4);
        k_edge<<<N_EDGES / (16 * 4 * 4), 256, 0, stream>>>(ef, nf, W0, b0, W1, b1, src, dst, out);
    }

    // out = rst @ Wa + ba (in place)
    k_out<<<(N_NODES / 16 + 3) / 4, 256, 0, stream>>>(Wa, ba, out);
}